// Round 4
// baseline (142.108 us; speedup 1.0000x reference)
//
#include <hip/hip_runtime.h>
#include <math.h>

#define N_AG 8192
#define SD 64
#define HD 128
#define CD 32
#define AD 8

// workspace layout (floats)
#define P_OFF     0                       // N_AG*HD
#define W2C_OFF   (N_AG*HD)               // HD*CD
#define BCP_OFF   (W2C_OFF + HD*CD)       // CD
#define MSUM_OFF  (BCP_OFF + CD)          // CD
#define HSUM_OFF  (MSUM_OFF + CD)         // HD
#define G_OFF     (HSUM_OFF + HD)         // HD

// ---------------- K0: W2c = W2 @ Wc (128x32), bc' = b2@Wc + bc; zero accumulators
__global__ void k0_pre(const float* __restrict__ W2, const float* __restrict__ b2,
                       const float* __restrict__ Wc, const float* __restrict__ bc,
                       float* __restrict__ ws) {
    float* W2c  = ws + W2C_OFF;
    float* bcp  = ws + BCP_OFF;
    float* msum = ws + MSUM_OFF;
    float* hsum = ws + HSUM_OFF;
    int tid = threadIdx.x;
    if (blockIdx.x < 16) {
        int idx = blockIdx.x * 256 + tid;     // [0, 4096)
        int i = idx >> 5, c = idx & 31;
        float s = 0.f;
        #pragma unroll 8
        for (int k = 0; k < HD; ++k) s += W2[i*HD + k] * Wc[k*CD + c];
        W2c[idx] = s;
    } else {
        if (tid < CD) {
            float s = bc[tid];
            for (int k = 0; k < HD; ++k) s += b2[k] * Wc[k*CD + tid];
            bcp[tid] = s;
            msum[tid] = 0.f;
        }
        if (tid >= 64 && tid < 64 + HD) hsum[tid - 64] = 0.f;
    }
}

// ---------------- K1: P = states@W1a + b1 (store), msgs = l2norm(relu(P)@W2c + bc'),
//                     accumulate sum of msgs into msum[32]
#define APB1 16
__global__ void k1_phaseA(const float* __restrict__ X, const float* __restrict__ W1,
                          const float* __restrict__ b1, float* __restrict__ ws) {
    const float* W2c = ws + W2C_OFF;
    const float* bcp = ws + BCP_OFF;
    float* P    = ws + P_OFF;
    float* msum = ws + MSUM_OFF;
    __shared__ float sX[APB1][SD];
    __shared__ float sH[APB1][HD + 1];
    __shared__ float sM[APB1][CD + 1];
    __shared__ float sR[APB1];
    int tid = threadIdx.x;                 // 256
    int a0 = blockIdx.x * APB1;
    for (int i = tid; i < APB1 * SD; i += 256) sX[i >> 6][i & 63] = X[a0 * SD + i];
    __syncthreads();
    // P phase: APB1*128 outputs, each a 64-dot
    for (int idx = tid; idx < APB1 * HD; idx += 256) {
        int ag = idx >> 7, c = idx & 127;
        float s = b1[c];
        #pragma unroll
        for (int k = 0; k < SD; ++k) s += sX[ag][k] * W1[k*HD + c];
        P[(a0 + ag)*HD + c] = s;
        sH[ag][c] = fmaxf(s, 0.f);
    }
    __syncthreads();
    // M phase: APB1*32 outputs, each a 128-dot against W2c
    for (int idx = tid; idx < APB1 * CD; idx += 256) {
        int ag = idx >> 5, c = idx & 31;
        float s = bcp[c];
        #pragma unroll 16
        for (int k = 0; k < HD; ++k) s += sH[ag][k] * W2c[k*CD + c];
        sM[ag][c] = s;
    }
    __syncthreads();
    if (tid < APB1) {
        float ss = 0.f;
        for (int c = 0; c < CD; ++c) { float m = sM[tid][c]; ss += m * m; }
        sR[tid] = 1.f / fmaxf(sqrtf(ss), 1e-12f);
    }
    __syncthreads();
    if (tid < CD) {
        float s = 0.f;
        for (int ag = 0; ag < APB1; ++ag) s += sM[ag][tid] * sR[ag];
        atomicAdd(&msum[tid], s);
    }
}

// ---------------- K2: cvec = (msum/N)@W1b; hsum += colsum(relu(P + cvec))
#define APB2 16
__global__ void k2_phaseB(const float* __restrict__ W1, float* __restrict__ ws) {
    const float* P    = ws + P_OFF;
    const float* msum = ws + MSUM_OFF;
    float* hsum = ws + HSUM_OFF;
    __shared__ float cvec[HD];
    __shared__ float red[256];
    int tid = threadIdx.x;                 // 256
    if (tid < HD) {
        float s = 0.f;
        #pragma unroll
        for (int k = 0; k < CD; ++k) s += msum[k] * W1[(SD + k)*HD + tid];
        cvec[tid] = s * (1.f / (float)N_AG);
    }
    __syncthreads();
    int c = tid & 127, half = tid >> 7;
    int a0 = blockIdx.x * APB2;
    float part = 0.f;
    for (int ag = half; ag < APB2; ag += 2)
        part += fmaxf(P[(a0 + ag)*HD + c] + cvec[c], 0.f);
    red[tid] = part;
    __syncthreads();
    if (tid < HD) atomicAdd(&hsum[tid], red[tid] + red[tid + 128]);
}

// ---------------- K3: g = relu(((hsum/N)@W2 + b2)@Wg + bg)   (single 128-thread block)
__global__ void k3_gvec(const float* __restrict__ W2, const float* __restrict__ b2,
                        const float* __restrict__ Wg, const float* __restrict__ bg,
                        float* __restrict__ ws) {
    const float* hsum = ws + HSUM_OFF;
    float* g = ws + G_OFF;
    __shared__ float hm[HD];
    __shared__ float u[HD];
    int t = threadIdx.x;                   // 128
    hm[t] = hsum[t] * (1.f / (float)N_AG);
    __syncthreads();
    float s = b2[t];
    #pragma unroll 16
    for (int k = 0; k < HD; ++k) s += hm[k] * W2[k*HD + t];
    u[t] = s;
    __syncthreads();
    float s2 = bg[t];
    #pragma unroll 16
    for (int k = 0; k < HD; ++k) s2 += u[k] * Wg[k*HD + t];
    g[t] = fmaxf(s2, 0.f);
}

// ---------------- K4: one wave per agent — H = l2norm(g + 0.01*noise), heads
__global__ void k4_out(const float* __restrict__ noise,
                       const float* __restrict__ Wp, const float* __restrict__ bp,
                       const float* __restrict__ Wv, const float* __restrict__ bv,
                       const float* __restrict__ Wr, const float* __restrict__ br,
                       const float* __restrict__ ws, float* __restrict__ out) {
    const float* g = ws + G_OFF;
    int gtid = blockIdx.x * blockDim.x + threadIdx.x;
    int a = gtid >> 6;
    int lane = threadIdx.x & 63;
    if (a >= N_AG) return;
    float v0 = g[lane]      + 0.01f * noise[a*HD + lane];
    float v1 = g[lane + 64] + 0.01f * noise[a*HD + 64 + lane];
    float ss = v0 * v0 + v1 * v1;
    #pragma unroll
    for (int off = 32; off; off >>= 1) ss += __shfl_xor(ss, off);
    float rinv = 1.f / fmaxf(sqrtf(ss), 1e-12f);
    float h0 = v0 * rinv, h1 = v1 * rinv;
    float* outH = out;
    float* outA = out + N_AG * HD;
    float* outV = outA + N_AG * AD;
    float* outR = outV + N_AG;
    outH[a*HD + lane]      = h0;
    outH[a*HD + 64 + lane] = h1;
    float acc[12];
    #pragma unroll
    for (int j = 0; j < 8; ++j)
        acc[j] = h0 * Wp[lane*AD + j] + h1 * Wp[(lane + 64)*AD + j];
    acc[8] = h0 * Wv[lane] + h1 * Wv[lane + 64];
    #pragma unroll
    for (int j = 0; j < 3; ++j)
        acc[9 + j] = h0 * Wr[lane*3 + j] + h1 * Wr[(lane + 64)*3 + j];
    #pragma unroll
    for (int j = 0; j < 12; ++j) {
        #pragma unroll
        for (int off = 32; off; off >>= 1) acc[j] += __shfl_xor(acc[j], off);
    }
    if (lane < 8) {
        outA[a*AD + lane] = tanhf(acc[lane] + bp[lane]);
    } else if (lane == 8) {
        outV[a] = acc[8] + bv[0];
    } else if (lane >= 9 && lane < 12) {
        float l0 = acc[9] + br[0], l1 = acc[10] + br[1], l2 = acc[11] + br[2];
        float m = fmaxf(l0, fmaxf(l1, l2));
        float e0 = expf(l0 - m), e1 = expf(l1 - m), e2 = expf(l2 - m);
        float denom = e0 + e1 + e2;
        float mine = (lane == 9) ? e0 : (lane == 10) ? e1 : e2;
        outR[a*3 + (lane - 9)] = mine / denom;
    }
}

extern "C" void kernel_launch(void* const* d_in, const int* in_sizes, int n_in,
                              void* d_out, int out_size, void* d_ws, size_t ws_size,
                              hipStream_t stream) {
    const float* states = (const float*)d_in[0];
    const float* noise  = (const float*)d_in[1];
    const float* W1 = (const float*)d_in[2];
    const float* b1 = (const float*)d_in[3];
    const float* W2 = (const float*)d_in[4];
    const float* b2 = (const float*)d_in[5];
    const float* Wc = (const float*)d_in[6];
    const float* bc = (const float*)d_in[7];
    const float* Wg = (const float*)d_in[8];
    const float* bg = (const float*)d_in[9];
    const float* Wp = (const float*)d_in[10];
    const float* bp = (const float*)d_in[11];
    const float* Wv = (const float*)d_in[12];
    const float* bv = (const float*)d_in[13];
    const float* Wr = (const float*)d_in[14];
    const float* br = (const float*)d_in[15];
    float* ws  = (float*)d_ws;
    float* out = (float*)d_out;

    hipLaunchKernelGGL(k0_pre,   dim3(17),           dim3(256), 0, stream, W2, b2, Wc, bc, ws);
    hipLaunchKernelGGL(k1_phaseA,dim3(N_AG / APB1),  dim3(256), 0, stream, states, W1, b1, ws);
    hipLaunchKernelGGL(k2_phaseB,dim3(N_AG / APB2),  dim3(256), 0, stream, W1, ws);
    hipLaunchKernelGGL(k3_gvec,  dim3(1),            dim3(128), 0, stream, W2, b2, Wg, bg, ws);
    hipLaunchKernelGGL(k4_out,   dim3(N_AG / 4),     dim3(256), 0, stream, noise, Wp, bp, Wv, bv, Wr, br, ws, out);
}